// Round 1
// baseline (1341.560 us; speedup 1.0000x reference)
//
#include <hip/hip_runtime.h>
#include <math.h>

#define N_TOK 512
#define D_DIM 768
#define G_NUM 4
#define E_NUM 8
#define GE 32
#define M_DIM 3072
#define NSEL 4

#define BM 32
#define BN 128
#define BK 16
#define KSPLIT 4

// ---------------- routing ----------------
__global__ void route_kernel(const float* __restrict__ x, const float* __restrict__ Wg,
                             const float* __restrict__ bg, const float* __restrict__ Wge,
                             const float* __restrict__ bge,
                             int* __restrict__ sel_e, float* __restrict__ sel_w,
                             int* __restrict__ counts) {
  int t = blockIdx.x * blockDim.x + threadIdx.x;
  if (t >= N_TOK) return;
  const float* xr = x + (size_t)t * D_DIM;

  // group logits
  float gl[G_NUM];
#pragma unroll
  for (int g = 0; g < G_NUM; ++g) gl[g] = 0.f;
  for (int k = 0; k < D_DIM; ++k) {
    float xv = xr[k];
    const float* w = Wg + (size_t)k * G_NUM;
#pragma unroll
    for (int g = 0; g < G_NUM; ++g) gl[g] += xv * w[g];
  }
#pragma unroll
  for (int g = 0; g < G_NUM; ++g) gl[g] += bg[g];

  // top-2 groups (strict > keeps first index on ties, matching lax.top_k)
  int g0 = 0;
#pragma unroll
  for (int g = 1; g < G_NUM; ++g) if (gl[g] > gl[g0]) g0 = g;
  int g1 = -1;
#pragma unroll
  for (int g = 0; g < G_NUM; ++g) {
    if (g == g0) continue;
    if (g1 < 0 || gl[g] > gl[g1]) g1 = g;
  }
  float egap = expf(gl[g1] - gl[g0]);   // v1 <= v0
  float gg0 = 1.f / (1.f + egap);
  float gg1 = egap * gg0;

  int gsel[2] = {g0, g1};
  float ggate[2] = {gg0, gg1};

  for (int j = 0; j < 2; ++j) {
    int g = gsel[j];
    float el[E_NUM];
#pragma unroll
    for (int e = 0; e < E_NUM; ++e) el[e] = 0.f;
    for (int k = 0; k < D_DIM; ++k) {
      float xv = xr[k];
      const float* w = Wge + ((size_t)g * D_DIM + k) * E_NUM;
#pragma unroll
      for (int e = 0; e < E_NUM; ++e) el[e] += xv * w[e];
    }
#pragma unroll
    for (int e = 0; e < E_NUM; ++e) el[e] += bge[g * E_NUM + e];

    int e0 = 0;
#pragma unroll
    for (int e = 1; e < E_NUM; ++e) if (el[e] > el[e0]) e0 = e;
    int e1 = -1;
#pragma unroll
    for (int e = 0; e < E_NUM; ++e) {
      if (e == e0) continue;
      if (e1 < 0 || el[e] > el[e1]) e1 = e;
    }
    float eg = expf(el[e1] - el[e0]);
    float inv = 1.f / (1.f + eg);
    float w0 = ggate[j] * inv;
    float w1 = ggate[j] * eg * inv;

    sel_e[t * NSEL + j * 2 + 0] = g * E_NUM + e0;
    sel_w[t * NSEL + j * 2 + 0] = w0;
    sel_e[t * NSEL + j * 2 + 1] = g * E_NUM + e1;
    sel_w[t * NSEL + j * 2 + 1] = w1;
    atomicAdd(&counts[g * E_NUM + e0], 1);
    atomicAdd(&counts[g * E_NUM + e1], 1);
  }
}

__global__ void scan_kernel(const int* __restrict__ counts, int* __restrict__ offsets) {
  if (threadIdx.x == 0 && blockIdx.x == 0) {
    int acc = 0;
    for (int e = 0; e < GE; ++e) { offsets[e] = acc; acc += counts[e]; }
    offsets[GE] = acc;
  }
}

__global__ void fill_kernel(const int* __restrict__ sel_e, const float* __restrict__ sel_w,
                            const int* __restrict__ offsets, int* __restrict__ counts2,
                            int* __restrict__ tok_id, float* __restrict__ tok_w) {
  int t = blockIdx.x * blockDim.x + threadIdx.x;
  if (t >= N_TOK) return;
#pragma unroll
  for (int j = 0; j < NSEL; ++j) {
    int e = sel_e[t * NSEL + j];
    int slot = atomicAdd(&counts2[e], 1);
    int p = offsets[e] + slot;
    tok_id[p] = t;
    tok_w[p] = sel_w[t * NSEL + j];
  }
}

// ---------------- fc1: h = gelu(X_e @ W1[e] + b1[e]) ----------------
__global__ __launch_bounds__(256) void fc1_kernel(const float* __restrict__ x,
    const float* __restrict__ W1, const float* __restrict__ b1,
    const int* __restrict__ offsets, const int* __restrict__ tok_id,
    float* __restrict__ h) {
  int e = blockIdx.x;
  int n0 = blockIdx.y * BN;
  int off = offsets[e];
  int cnt = offsets[e + 1] - off;
  if (cnt == 0) return;

  __shared__ float As[BM][BK + 1];
  __shared__ float Bs[BK][BN];

  int tid = threadIdx.x;
  int tx = tid & 31;   // 32 col groups * 4 cols = 128
  int ty = tid >> 5;   // 8 row groups * 4 rows = 32

  const float* Wbase = W1 + (size_t)e * D_DIM * M_DIM;

  for (int r0 = 0; r0 < cnt; r0 += BM) {
    float acc[4][4];
#pragma unroll
    for (int i = 0; i < 4; ++i)
#pragma unroll
      for (int j = 0; j < 4; ++j) acc[i][j] = 0.f;

    for (int k0 = 0; k0 < D_DIM; k0 += BK) {
      // stage A (gathered token rows), 512 elems
#pragma unroll
      for (int j = 0; j < 2; ++j) {
        int idx = tid + j * 256;
        int r = idx >> 4, kk = idx & 15;
        int rr = r0 + r;
        float v = 0.f;
        if (rr < cnt) v = x[(size_t)tok_id[off + rr] * D_DIM + k0 + kk];
        As[r][kk] = v;
      }
      // stage B (weight tile), 2048 elems via float4
#pragma unroll
      for (int j = 0; j < 2; ++j) {
        int idx = tid + j * 256;
        int kk = idx >> 5, n4 = (idx & 31) * 4;
        float4 v = *(const float4*)&Wbase[(size_t)(k0 + kk) * M_DIM + n0 + n4];
        *(float4*)&Bs[kk][n4] = v;
      }
      __syncthreads();
#pragma unroll
      for (int kk = 0; kk < BK; ++kk) {
        float a[4];
#pragma unroll
        for (int i = 0; i < 4; ++i) a[i] = As[ty * 4 + i][kk];
        float4 b4 = *(float4*)&Bs[kk][tx * 4];
        float bv[4] = {b4.x, b4.y, b4.z, b4.w};
#pragma unroll
        for (int i = 0; i < 4; ++i)
#pragma unroll
          for (int j = 0; j < 4; ++j) acc[i][j] += a[i] * bv[j];
      }
      __syncthreads();
    }
    // epilogue: bias + exact gelu
#pragma unroll
    for (int i = 0; i < 4; ++i) {
      int rr = r0 + ty * 4 + i;
      if (rr >= cnt) break;
      size_t hrow = (size_t)(off + rr) * M_DIM + n0 + tx * 4;
#pragma unroll
      for (int j = 0; j < 4; ++j) {
        float v = acc[i][j] + b1[e * M_DIM + n0 + tx * 4 + j];
        float ge = 0.5f * v * (1.f + erff(v * 0.70710678118654752f));
        h[hrow + j] = ge;
      }
    }
  }
}

// ---------------- fc2: out[t] += w * (h_e @ W2[e] + b2[e]) ----------------
__global__ __launch_bounds__(256) void fc2_kernel(const float* __restrict__ h,
    const float* __restrict__ W2, const float* __restrict__ b2,
    const int* __restrict__ offsets, const int* __restrict__ tok_id,
    const float* __restrict__ tok_w, float* __restrict__ out) {
  int e = blockIdx.x;
  int n0 = blockIdx.y * BN;
  int kbase = blockIdx.z * (M_DIM / KSPLIT);
  int off = offsets[e];
  int cnt = offsets[e + 1] - off;
  if (cnt == 0) return;

  __shared__ float As[BM][BK + 1];
  __shared__ float Bs[BK][BN];

  int tid = threadIdx.x;
  int tx = tid & 31;
  int ty = tid >> 5;

  const float* Wbase = W2 + (size_t)e * M_DIM * D_DIM;

  for (int r0 = 0; r0 < cnt; r0 += BM) {
    float acc[4][4];
#pragma unroll
    for (int i = 0; i < 4; ++i)
#pragma unroll
      for (int j = 0; j < 4; ++j) acc[i][j] = 0.f;

    for (int k0 = kbase; k0 < kbase + M_DIM / KSPLIT; k0 += BK) {
#pragma unroll
      for (int j = 0; j < 2; ++j) {
        int idx = tid + j * 256;
        int r = idx >> 4, kk = idx & 15;
        int rr = r0 + r;
        float v = 0.f;
        if (rr < cnt) v = h[(size_t)(off + rr) * M_DIM + k0 + kk];
        As[r][kk] = v;
      }
#pragma unroll
      for (int j = 0; j < 2; ++j) {
        int idx = tid + j * 256;
        int kk = idx >> 5, n4 = (idx & 31) * 4;
        float4 v = *(const float4*)&Wbase[(size_t)(k0 + kk) * D_DIM + n0 + n4];
        *(float4*)&Bs[kk][n4] = v;
      }
      __syncthreads();
#pragma unroll
      for (int kk = 0; kk < BK; ++kk) {
        float a[4];
#pragma unroll
        for (int i = 0; i < 4; ++i) a[i] = As[ty * 4 + i][kk];
        float4 b4 = *(float4*)&Bs[kk][tx * 4];
        float bv[4] = {b4.x, b4.y, b4.z, b4.w};
#pragma unroll
        for (int i = 0; i < 4; ++i)
#pragma unroll
          for (int j = 0; j < 4; ++j) acc[i][j] += a[i] * bv[j];
      }
      __syncthreads();
    }
    // epilogue: weighted atomic combine into out
#pragma unroll
    for (int i = 0; i < 4; ++i) {
      int rr = r0 + ty * 4 + i;
      if (rr >= cnt) break;
      int t = tok_id[off + rr];
      float w = tok_w[off + rr];
#pragma unroll
      for (int j = 0; j < 4; ++j) {
        int c = n0 + tx * 4 + j;
        float v = acc[i][j];
        if (blockIdx.z == 0) v += b2[e * D_DIM + c];
        atomicAdd(&out[(size_t)t * D_DIM + c], w * v);
      }
    }
  }
}

// ---------------- launch ----------------
extern "C" void kernel_launch(void* const* d_in, const int* in_sizes, int n_in,
                              void* d_out, int out_size, void* d_ws, size_t ws_size,
                              hipStream_t stream) {
  const float* x   = (const float*)d_in[0];
  const float* Wg  = (const float*)d_in[1];
  const float* bg  = (const float*)d_in[2];
  const float* Wge = (const float*)d_in[3];
  const float* bge = (const float*)d_in[4];
  const float* W1  = (const float*)d_in[5];
  const float* b1  = (const float*)d_in[6];
  const float* W2  = (const float*)d_in[7];
  const float* b2  = (const float*)d_in[8];
  float* out = (float*)d_out;

  char* ws = (char*)d_ws;
  int*   counts  = (int*)(ws + 0);        // 32 ints
  int*   counts2 = (int*)(ws + 128);      // 32 ints
  int*   offsets = (int*)(ws + 256);      // 33 ints
  int*   sel_e   = (int*)(ws + 512);      // 2048 ints
  float* sel_w   = (float*)(ws + 8704);   // 2048 floats
  int*   tok_id  = (int*)(ws + 16896);    // 2048 ints
  float* tok_w   = (float*)(ws + 25088);  // 2048 floats
  float* h       = (float*)(ws + 33280);  // 2048*3072 floats (~25.2 MB)

  hipMemsetAsync(ws, 0, 256, stream);                              // counts, counts2
  hipMemsetAsync(d_out, 0, (size_t)out_size * sizeof(float), stream);

  route_kernel<<<8, 64, 0, stream>>>(x, Wg, bg, Wge, bge, sel_e, sel_w, counts);
  scan_kernel<<<1, 64, 0, stream>>>(counts, offsets);
  fill_kernel<<<8, 64, 0, stream>>>(sel_e, sel_w, offsets, counts2, tok_id, tok_w);
  fc1_kernel<<<dim3(GE, M_DIM / BN), 256, 0, stream>>>(x, W1, b1, offsets, tok_id, h);
  fc2_kernel<<<dim3(GE, D_DIM / BN, KSPLIT), 256, 0, stream>>>(h, W2, b2, offsets, tok_id, tok_w, out);
}

// Round 2
// 929.150 us; speedup vs baseline: 1.4439x; 1.4439x over previous
//
#include <hip/hip_runtime.h>
#include <math.h>

#define N_TOK 512
#define D_DIM 768
#define G_NUM 4
#define E_NUM 8
#define GE 32
#define M_DIM 3072
#define NSEL 4

#define BM 64
#define BN 128
#define BKT 32
#define LDS_STRIDE 40   // bf16 elems; 80B row pitch -> conflict-light b128 access

typedef __bf16 bf16x8 __attribute__((ext_vector_type(8)));
typedef float f32x16 __attribute__((ext_vector_type(16)));

// ---------------- routing ----------------
__global__ void route_kernel(const float* __restrict__ x, const float* __restrict__ Wg,
                             const float* __restrict__ bg, const float* __restrict__ Wge,
                             const float* __restrict__ bge,
                             int* __restrict__ sel_e, float* __restrict__ sel_w,
                             int* __restrict__ counts) {
  int t = blockIdx.x * blockDim.x + threadIdx.x;
  if (t >= N_TOK) return;
  const float* xr = x + (size_t)t * D_DIM;

  float gl[G_NUM];
#pragma unroll
  for (int g = 0; g < G_NUM; ++g) gl[g] = 0.f;
  for (int k = 0; k < D_DIM; ++k) {
    float xv = xr[k];
    const float* w = Wg + (size_t)k * G_NUM;
#pragma unroll
    for (int g = 0; g < G_NUM; ++g) gl[g] += xv * w[g];
  }
#pragma unroll
  for (int g = 0; g < G_NUM; ++g) gl[g] += bg[g];

  int g0 = 0;
#pragma unroll
  for (int g = 1; g < G_NUM; ++g) if (gl[g] > gl[g0]) g0 = g;
  int g1 = -1;
#pragma unroll
  for (int g = 0; g < G_NUM; ++g) {
    if (g == g0) continue;
    if (g1 < 0 || gl[g] > gl[g1]) g1 = g;
  }
  float egap = expf(gl[g1] - gl[g0]);
  float gg0 = 1.f / (1.f + egap);
  float gg1 = egap * gg0;

  int gsel[2] = {g0, g1};
  float ggate[2] = {gg0, gg1};

  for (int j = 0; j < 2; ++j) {
    int g = gsel[j];
    float el[E_NUM];
#pragma unroll
    for (int e = 0; e < E_NUM; ++e) el[e] = 0.f;
    for (int k = 0; k < D_DIM; ++k) {
      float xv = xr[k];
      const float* w = Wge + ((size_t)g * D_DIM + k) * E_NUM;
#pragma unroll
      for (int e = 0; e < E_NUM; ++e) el[e] += xv * w[e];
    }
#pragma unroll
    for (int e = 0; e < E_NUM; ++e) el[e] += bge[g * E_NUM + e];

    int e0 = 0;
#pragma unroll
    for (int e = 1; e < E_NUM; ++e) if (el[e] > el[e0]) e0 = e;
    int e1 = -1;
#pragma unroll
    for (int e = 0; e < E_NUM; ++e) {
      if (e == e0) continue;
      if (e1 < 0 || el[e] > el[e1]) e1 = e;
    }
    float eg = expf(el[e1] - el[e0]);
    float inv = 1.f / (1.f + eg);

    sel_e[t * NSEL + j * 2 + 0] = g * E_NUM + e0;
    sel_w[t * NSEL + j * 2 + 0] = ggate[j] * inv;
    sel_e[t * NSEL + j * 2 + 1] = g * E_NUM + e1;
    sel_w[t * NSEL + j * 2 + 1] = ggate[j] * eg * inv;
    atomicAdd(&counts[g * E_NUM + e0], 1);
    atomicAdd(&counts[g * E_NUM + e1], 1);
  }
}

__global__ void scan_kernel(const int* __restrict__ counts, int* __restrict__ offsets) {
  if (threadIdx.x == 0 && blockIdx.x == 0) {
    int acc = 0;
    for (int e = 0; e < GE; ++e) { offsets[e] = acc; acc += counts[e]; }
    offsets[GE] = acc;
  }
}

__global__ void fill_kernel(const int* __restrict__ sel_e, const float* __restrict__ sel_w,
                            const int* __restrict__ offsets, int* __restrict__ counts2,
                            int* __restrict__ tok_id, float* __restrict__ tok_w) {
  int t = blockIdx.x * blockDim.x + threadIdx.x;
  if (t >= N_TOK) return;
#pragma unroll
  for (int j = 0; j < NSEL; ++j) {
    int e = sel_e[t * NSEL + j];
    int slot = atomicAdd(&counts2[e], 1);
    int p = offsets[e] + slot;
    tok_id[p] = t;
    tok_w[p] = sel_w[t * NSEL + j];
  }
}

// gather token rows -> bf16 Abuf[p][D]
__global__ void gather_kernel(const float* __restrict__ x, const int* __restrict__ tok_id,
                              __bf16* __restrict__ Abuf) {
  int p = blockIdx.x;
  int t = tok_id[p];
  int i = threadIdx.x;
  if (i < D_DIM / 4) {
    const float4 v = ((const float4*)(x + (size_t)t * D_DIM))[i];
    __bf16 o[4] = {(__bf16)v.x, (__bf16)v.y, (__bf16)v.z, (__bf16)v.w};
    *(uint2*)(Abuf + (size_t)p * D_DIM + 4 * i) = *(uint2*)o;
  }
}

// ---------------- fc1: h = gelu(A @ W1 + b1), bf16 MFMA ----------------
__global__ __launch_bounds__(256, 2) void fc1_mfma(
    const __bf16* __restrict__ Abuf, const float* __restrict__ W1,
    const float* __restrict__ b1, const int* __restrict__ offsets,
    __bf16* __restrict__ h) {
  int e = blockIdx.x;
  int n0 = blockIdx.y * BN;
  int off = offsets[e];
  int cnt = offsets[e + 1] - off;
  if (cnt == 0) return;

  __shared__ __align__(16) __bf16 Al[BM * LDS_STRIDE];
  __shared__ __align__(16) __bf16 Bl[BN * LDS_STRIDE];

  int tid = threadIdx.x;
  int w = tid >> 6, lane = tid & 63;
  int l31 = lane & 31, lh = lane >> 5;

  int sa_row = tid >> 2;             // 0..63
  int sa_kp = (tid & 3) * 8;         // 0,8,16,24
  int sb_n = tid & 127;              // 0..127
  int sb_kg = (tid >> 7) * 16;       // 0 or 16

  const float* Wb = W1 + (size_t)e * D_DIM * M_DIM + n0 + sb_n;
  const int NKT = D_DIM / BKT;       // 24

  for (int r0 = 0; r0 < cnt; r0 += BM) {
    f32x16 acc[2];
#pragma unroll
    for (int mt = 0; mt < 2; ++mt)
#pragma unroll
      for (int r = 0; r < 16; ++r) acc[mt][r] = 0.f;

    const __bf16* Arow = Abuf + (size_t)(off + r0 + sa_row) * D_DIM + sa_kp;

    uint4 ra = *(const uint4*)Arow;
    float rb[16];
#pragma unroll
    for (int i = 0; i < 16; ++i) rb[i] = Wb[(size_t)(sb_kg + i) * M_DIM];

    for (int kt = 0; kt < NKT; ++kt) {
      __syncthreads();
      *(uint4*)(Al + sa_row * LDS_STRIDE + sa_kp) = ra;
      {
        bf16x8 lo, hi;
#pragma unroll
        for (int i = 0; i < 8; ++i) { lo[i] = (__bf16)rb[i]; hi[i] = (__bf16)rb[8 + i]; }
        *(bf16x8*)(Bl + sb_n * LDS_STRIDE + sb_kg) = lo;
        *(bf16x8*)(Bl + sb_n * LDS_STRIDE + sb_kg + 8) = hi;
      }
      uint4 ra_n = ra;
      float rb_n[16];
#pragma unroll
      for (int i = 0; i < 16; ++i) rb_n[i] = rb[i];
      if (kt + 1 < NKT) {
        int k0 = (kt + 1) * BKT;
        ra_n = *(const uint4*)(Arow + k0);
#pragma unroll
        for (int i = 0; i < 16; ++i) rb_n[i] = Wb[(size_t)(k0 + sb_kg + i) * M_DIM];
      }
      __syncthreads();
#pragma unroll
      for (int ks = 0; ks < 2; ++ks) {
        bf16x8 b  = *(bf16x8*)(Bl + (w * 32 + l31) * LDS_STRIDE + ks * 16 + lh * 8);
        bf16x8 a0 = *(bf16x8*)(Al + (l31) * LDS_STRIDE + ks * 16 + lh * 8);
        bf16x8 a1 = *(bf16x8*)(Al + (32 + l31) * LDS_STRIDE + ks * 16 + lh * 8);
        acc[0] = __builtin_amdgcn_mfma_f32_32x32x16_bf16(a0, b, acc[0], 0, 0, 0);
        acc[1] = __builtin_amdgcn_mfma_f32_32x32x16_bf16(a1, b, acc[1], 0, 0, 0);
      }
      ra = ra_n;
#pragma unroll
      for (int i = 0; i < 16; ++i) rb[i] = rb_n[i];
    }

    int col = n0 + w * 32 + l31;
    float bias = b1[e * M_DIM + col];
#pragma unroll
    for (int mt = 0; mt < 2; ++mt) {
#pragma unroll
      for (int r = 0; r < 16; ++r) {
        int row = mt * 32 + (r & 3) + 8 * (r >> 2) + 4 * lh;
        if (r0 + row < cnt) {
          float v = acc[mt][r] + bias;
          v = 0.5f * v * (1.f + erff(v * 0.70710678118654752f));
          h[(size_t)(off + r0 + row) * M_DIM + col] = (__bf16)v;
        }
      }
    }
  }
}

// ---------------- fc2: out[t] += w * (h @ W2 + b2), bf16 MFMA ----------------
__global__ __launch_bounds__(256, 2) void fc2_mfma(
    const __bf16* __restrict__ h, const float* __restrict__ W2,
    const float* __restrict__ b2, const int* __restrict__ offsets,
    const int* __restrict__ tok_id, const float* __restrict__ tok_w,
    float* __restrict__ out) {
  int e = blockIdx.x;
  int n0 = blockIdx.y * BN;          // over D: 6 tiles
  int kbase = blockIdx.z * (M_DIM / 4);
  int off = offsets[e];
  int cnt = offsets[e + 1] - off;
  if (cnt == 0) return;

  __shared__ __align__(16) __bf16 Al[BM * LDS_STRIDE];
  __shared__ __align__(16) __bf16 Bl[BN * LDS_STRIDE];

  int tid = threadIdx.x;
  int w = tid >> 6, lane = tid & 63;
  int l31 = lane & 31, lh = lane >> 5;

  int sa_row = tid >> 2;
  int sa_kp = (tid & 3) * 8;
  int sb_n = tid & 127;
  int sb_kg = (tid >> 7) * 16;

  const float* Wb = W2 + (size_t)e * M_DIM * D_DIM + n0 + sb_n;
  const int NKT = (M_DIM / 4) / BKT; // 24

  for (int r0 = 0; r0 < cnt; r0 += BM) {
    f32x16 acc[2];
#pragma unroll
    for (int mt = 0; mt < 2; ++mt)
#pragma unroll
      for (int r = 0; r < 16; ++r) acc[mt][r] = 0.f;

    const __bf16* Arow = h + (size_t)(off + r0 + sa_row) * M_DIM + kbase + sa_kp;

    uint4 ra = *(const uint4*)Arow;
    float rb[16];
#pragma unroll
    for (int i = 0; i < 16; ++i) rb[i] = Wb[(size_t)(kbase + sb_kg + i) * D_DIM];

    for (int kt = 0; kt < NKT; ++kt) {
      __syncthreads();
      *(uint4*)(Al + sa_row * LDS_STRIDE + sa_kp) = ra;
      {
        bf16x8 lo, hi;
#pragma unroll
        for (int i = 0; i < 8; ++i) { lo[i] = (__bf16)rb[i]; hi[i] = (__bf16)rb[8 + i]; }
        *(bf16x8*)(Bl + sb_n * LDS_STRIDE + sb_kg) = lo;
        *(bf16x8*)(Bl + sb_n * LDS_STRIDE + sb_kg + 8) = hi;
      }
      uint4 ra_n = ra;
      float rb_n[16];
#pragma unroll
      for (int i = 0; i < 16; ++i) rb_n[i] = rb[i];
      if (kt + 1 < NKT) {
        int k0 = (kt + 1) * BKT;
        ra_n = *(const uint4*)(Arow + k0);
#pragma unroll
        for (int i = 0; i < 16; ++i)
          rb_n[i] = Wb[(size_t)(kbase + k0 + sb_kg + i) * D_DIM];
      }
      __syncthreads();
#pragma unroll
      for (int ks = 0; ks < 2; ++ks) {
        bf16x8 b  = *(bf16x8*)(Bl + (w * 32 + l31) * LDS_STRIDE + ks * 16 + lh * 8);
        bf16x8 a0 = *(bf16x8*)(Al + (l31) * LDS_STRIDE + ks * 16 + lh * 8);
        bf16x8 a1 = *(bf16x8*)(Al + (32 + l31) * LDS_STRIDE + ks * 16 + lh * 8);
        acc[0] = __builtin_amdgcn_mfma_f32_32x32x16_bf16(a0, b, acc[0], 0, 0, 0);
        acc[1] = __builtin_amdgcn_mfma_f32_32x32x16_bf16(a1, b, acc[1], 0, 0, 0);
      }
      ra = ra_n;
#pragma unroll
      for (int i = 0; i < 16; ++i) rb[i] = rb_n[i];
    }

    int col = n0 + w * 32 + l31;
    float bias = (blockIdx.z == 0) ? b2[e * D_DIM + col] : 0.f;
#pragma unroll
    for (int mt = 0; mt < 2; ++mt) {
#pragma unroll
      for (int r = 0; r < 16; ++r) {
        int row = mt * 32 + (r & 3) + 8 * (r >> 2) + 4 * lh;
        if (r0 + row < cnt) {
          int p = off + r0 + row;
          int t = tok_id[p];
          float wgt = tok_w[p];
          atomicAdd(&out[(size_t)t * D_DIM + col], wgt * (acc[mt][r] + bias));
        }
      }
    }
  }
}

// ---------------- launch ----------------
extern "C" void kernel_launch(void* const* d_in, const int* in_sizes, int n_in,
                              void* d_out, int out_size, void* d_ws, size_t ws_size,
                              hipStream_t stream) {
  const float* x   = (const float*)d_in[0];
  const float* Wg  = (const float*)d_in[1];
  const float* bg  = (const float*)d_in[2];
  const float* Wge = (const float*)d_in[3];
  const float* bge = (const float*)d_in[4];
  const float* W1  = (const float*)d_in[5];
  const float* b1  = (const float*)d_in[6];
  const float* W2  = (const float*)d_in[7];
  const float* b2  = (const float*)d_in[8];
  float* out = (float*)d_out;

  char* ws = (char*)d_ws;
  int*    counts  = (int*)(ws + 0);
  int*    counts2 = (int*)(ws + 128);
  int*    offsets = (int*)(ws + 256);
  int*    sel_e   = (int*)(ws + 512);
  float*  sel_w   = (float*)(ws + 8704);
  int*    tok_id  = (int*)(ws + 16896);
  float*  tok_w   = (float*)(ws + 25088);
  __bf16* Abuf    = (__bf16*)(ws + 33280);             // (2048+64) x 768 bf16
  __bf16* h       = (__bf16*)(ws + 33280 + 3244032);   // (2048+64) x 3072 bf16

  hipMemsetAsync(ws, 0, 256, stream);
  hipMemsetAsync(d_out, 0, (size_t)out_size * sizeof(float), stream);

  route_kernel<<<8, 64, 0, stream>>>(x, Wg, bg, Wge, bge, sel_e, sel_w, counts);
  scan_kernel<<<1, 64, 0, stream>>>(counts, offsets);
  fill_kernel<<<8, 64, 0, stream>>>(sel_e, sel_w, offsets, counts2, tok_id, tok_w);
  gather_kernel<<<2048, 192, 0, stream>>>(x, tok_id, Abuf);
  fc1_mfma<<<dim3(GE, M_DIM / BN), 256, 0, stream>>>(Abuf, W1, b1, offsets, h);
  fc2_mfma<<<dim3(GE, D_DIM / BN, 4), 256, 0, stream>>>(h, W2, b2, offsets, tok_id, tok_w, out);
}

// Round 3
// 715.324 us; speedup vs baseline: 1.8755x; 1.2989x over previous
//
#include <hip/hip_runtime.h>
#include <math.h>

#define N_TOK 512
#define D_DIM 768
#define G_NUM 4
#define E_NUM 8
#define GE 32
#define M_DIM 3072
#define NSEL 4

#define BM 64
#define BN 128
#define BKT 32
#define LDS_STRIDE 40   // bf16 elems; 80B row pitch -> conflict-light b128 access

typedef __bf16 bf16x8 __attribute__((ext_vector_type(8)));
typedef float f32x16 __attribute__((ext_vector_type(16)));

// ---------------- routing: one 64-lane wave per token ----------------
__global__ __launch_bounds__(64) void route_kernel(
    const float* __restrict__ x, const float* __restrict__ Wg,
    const float* __restrict__ bg, const float* __restrict__ Wge,
    const float* __restrict__ bge,
    int* __restrict__ sel_e, float* __restrict__ sel_w,
    int* __restrict__ counts) {
  int t = blockIdx.x;
  int lane = threadIdx.x;
  const float* xr = x + (size_t)t * D_DIM;

  // each lane owns 12 consecutive k
  float xv[12];
#pragma unroll
  for (int i = 0; i < 12; ++i) xv[i] = xr[lane * 12 + i];

  float gl[G_NUM] = {0.f, 0.f, 0.f, 0.f};
  float el[G_NUM][E_NUM];
#pragma unroll
  for (int g = 0; g < G_NUM; ++g)
#pragma unroll
    for (int e = 0; e < E_NUM; ++e) el[g][e] = 0.f;

#pragma unroll
  for (int i = 0; i < 12; ++i) {
    int k = lane * 12 + i;
    float v = xv[i];
    float4 wg4 = *(const float4*)(Wg + (size_t)k * G_NUM);
    gl[0] += v * wg4.x; gl[1] += v * wg4.y; gl[2] += v * wg4.z; gl[3] += v * wg4.w;
#pragma unroll
    for (int g = 0; g < G_NUM; ++g) {
      const float4* we = (const float4*)(Wge + ((size_t)g * D_DIM + k) * E_NUM);
      float4 a = we[0], b = we[1];
      el[g][0] += v * a.x; el[g][1] += v * a.y; el[g][2] += v * a.z; el[g][3] += v * a.w;
      el[g][4] += v * b.x; el[g][5] += v * b.y; el[g][6] += v * b.z; el[g][7] += v * b.w;
    }
  }

  // butterfly reduce all 36 partials across the wave
#pragma unroll
  for (int m = 1; m < 64; m <<= 1) {
#pragma unroll
    for (int g = 0; g < G_NUM; ++g) gl[g] += __shfl_xor(gl[g], m);
#pragma unroll
    for (int g = 0; g < G_NUM; ++g)
#pragma unroll
      for (int e = 0; e < E_NUM; ++e) el[g][e] += __shfl_xor(el[g][e], m);
  }

  if (lane != 0) return;

#pragma unroll
  for (int g = 0; g < G_NUM; ++g) gl[g] += bg[g];
#pragma unroll
  for (int g = 0; g < G_NUM; ++g)
#pragma unroll
    for (int e = 0; e < E_NUM; ++e) el[g][e] += bge[g * E_NUM + e];

  // top-2 groups (strict > keeps first index on ties, matching lax.top_k)
  int g0 = 0;
#pragma unroll
  for (int g = 1; g < G_NUM; ++g) if (gl[g] > gl[g0]) g0 = g;
  int g1 = -1;
#pragma unroll
  for (int g = 0; g < G_NUM; ++g) {
    if (g == g0) continue;
    if (g1 < 0 || gl[g] > gl[g1]) g1 = g;
  }
  float egap = expf(gl[g1] - gl[g0]);
  float gg0 = 1.f / (1.f + egap);

  int gsel[2] = {g0, g1};
  float ggate[2] = {gg0, egap * gg0};

#pragma unroll
  for (int j = 0; j < 2; ++j) {
    int g = gsel[j];
    int e0 = 0;
#pragma unroll
    for (int e = 1; e < E_NUM; ++e) if (el[g][e] > el[g][e0]) e0 = e;
    int e1 = -1;
#pragma unroll
    for (int e = 0; e < E_NUM; ++e) {
      if (e == e0) continue;
      if (e1 < 0 || el[g][e] > el[g][e1]) e1 = e;
    }
    float eg = expf(el[g][e1] - el[g][e0]);
    float inv = 1.f / (1.f + eg);

    sel_e[t * NSEL + j * 2 + 0] = g * E_NUM + e0;
    sel_w[t * NSEL + j * 2 + 0] = ggate[j] * inv;
    sel_e[t * NSEL + j * 2 + 1] = g * E_NUM + e1;
    sel_w[t * NSEL + j * 2 + 1] = ggate[j] * eg * inv;
    atomicAdd(&counts[g * E_NUM + e0], 1);
    atomicAdd(&counts[g * E_NUM + e1], 1);
  }
}

__global__ void scan_kernel(const int* __restrict__ counts, int* __restrict__ offsets) {
  if (threadIdx.x == 0 && blockIdx.x == 0) {
    int acc = 0;
    for (int e = 0; e < GE; ++e) { offsets[e] = acc; acc += counts[e]; }
    offsets[GE] = acc;
  }
}

__global__ void fill_kernel(const int* __restrict__ sel_e, const float* __restrict__ sel_w,
                            const int* __restrict__ offsets, int* __restrict__ counts2,
                            int* __restrict__ tok_id, float* __restrict__ tok_w) {
  int t = blockIdx.x * blockDim.x + threadIdx.x;
  if (t >= N_TOK) return;
#pragma unroll
  for (int j = 0; j < NSEL; ++j) {
    int e = sel_e[t * NSEL + j];
    int slot = atomicAdd(&counts2[e], 1);
    int p = offsets[e] + slot;
    tok_id[p] = t;
    tok_w[p] = sel_w[t * NSEL + j];
  }
}

// gather token rows -> bf16 Abuf[p][D]
__global__ void gather_kernel(const float* __restrict__ x, const int* __restrict__ tok_id,
                              __bf16* __restrict__ Abuf) {
  int p = blockIdx.x;
  int t = tok_id[p];
  int i = threadIdx.x;
  if (i < D_DIM / 4) {
    const float4 v = ((const float4*)(x + (size_t)t * D_DIM))[i];
    __bf16 o[4] = {(__bf16)v.x, (__bf16)v.y, (__bf16)v.z, (__bf16)v.w};
    *(uint2*)(Abuf + (size_t)p * D_DIM + 4 * i) = *(uint2*)o;
  }
}

// ---------------- fc1: h = gelu(A @ W1 + b1), bf16 MFMA ----------------
__global__ __launch_bounds__(256, 2) void fc1_mfma(
    const __bf16* __restrict__ Abuf, const float* __restrict__ W1,
    const float* __restrict__ b1, const int* __restrict__ offsets,
    __bf16* __restrict__ h) {
  int e = blockIdx.x;
  int n0 = blockIdx.y * BN;
  int off = offsets[e];
  int cnt = offsets[e + 1] - off;
  if (cnt == 0) return;

  __shared__ __align__(16) __bf16 Al[BM * LDS_STRIDE];
  __shared__ __align__(16) __bf16 Bl[BN * LDS_STRIDE];

  int tid = threadIdx.x;
  int w = tid >> 6, lane = tid & 63;
  int l31 = lane & 31, lh = lane >> 5;

  int sa_row = tid >> 2;             // 0..63
  int sa_kp = (tid & 3) * 8;         // 0,8,16,24
  int sb_n = tid & 127;              // 0..127
  int sb_kg = (tid >> 7) * 16;       // 0 or 16

  const float* Wb = W1 + (size_t)e * D_DIM * M_DIM + n0 + sb_n;
  const int NKT = D_DIM / BKT;       // 24

  for (int r0 = 0; r0 < cnt; r0 += BM) {
    f32x16 acc[2];
#pragma unroll
    for (int mt = 0; mt < 2; ++mt)
#pragma unroll
      for (int r = 0; r < 16; ++r) acc[mt][r] = 0.f;

    const __bf16* Arow = Abuf + (size_t)(off + r0 + sa_row) * D_DIM + sa_kp;

    uint4 ra = *(const uint4*)Arow;
    float rb[16];
#pragma unroll
    for (int i = 0; i < 16; ++i) rb[i] = Wb[(size_t)(sb_kg + i) * M_DIM];

    for (int kt = 0; kt < NKT; ++kt) {
      __syncthreads();
      *(uint4*)(Al + sa_row * LDS_STRIDE + sa_kp) = ra;
      {
        bf16x8 lo, hi;
#pragma unroll
        for (int i = 0; i < 8; ++i) { lo[i] = (__bf16)rb[i]; hi[i] = (__bf16)rb[8 + i]; }
        *(bf16x8*)(Bl + sb_n * LDS_STRIDE + sb_kg) = lo;
        *(bf16x8*)(Bl + sb_n * LDS_STRIDE + sb_kg + 8) = hi;
      }
      uint4 ra_n = ra;
      float rb_n[16];
#pragma unroll
      for (int i = 0; i < 16; ++i) rb_n[i] = rb[i];
      if (kt + 1 < NKT) {
        int k0 = (kt + 1) * BKT;
        ra_n = *(const uint4*)(Arow + k0);
#pragma unroll
        for (int i = 0; i < 16; ++i) rb_n[i] = Wb[(size_t)(k0 + sb_kg + i) * M_DIM];
      }
      __syncthreads();
#pragma unroll
      for (int ks = 0; ks < 2; ++ks) {
        bf16x8 b  = *(bf16x8*)(Bl + (w * 32 + l31) * LDS_STRIDE + ks * 16 + lh * 8);
        bf16x8 a0 = *(bf16x8*)(Al + (l31) * LDS_STRIDE + ks * 16 + lh * 8);
        bf16x8 a1 = *(bf16x8*)(Al + (32 + l31) * LDS_STRIDE + ks * 16 + lh * 8);
        acc[0] = __builtin_amdgcn_mfma_f32_32x32x16_bf16(a0, b, acc[0], 0, 0, 0);
        acc[1] = __builtin_amdgcn_mfma_f32_32x32x16_bf16(a1, b, acc[1], 0, 0, 0);
      }
      ra = ra_n;
#pragma unroll
      for (int i = 0; i < 16; ++i) rb[i] = rb_n[i];
    }

    int col = n0 + w * 32 + l31;
    float bias = b1[e * M_DIM + col];
#pragma unroll
    for (int mt = 0; mt < 2; ++mt) {
#pragma unroll
      for (int r = 0; r < 16; ++r) {
        int row = mt * 32 + (r & 3) + 8 * (r >> 2) + 4 * lh;
        if (r0 + row < cnt) {
          float v = acc[mt][r] + bias;
          v = 0.5f * v * (1.f + erff(v * 0.70710678118654752f));
          h[(size_t)(off + r0 + row) * M_DIM + col] = (__bf16)v;
        }
      }
    }
  }
}

// ---------------- fc2: out[t] += w * (h @ W2 + b2), bf16 MFMA ----------------
__global__ __launch_bounds__(256, 2) void fc2_mfma(
    const __bf16* __restrict__ h, const float* __restrict__ W2,
    const float* __restrict__ b2, const int* __restrict__ offsets,
    const int* __restrict__ tok_id, const float* __restrict__ tok_w,
    float* __restrict__ out) {
  int e = blockIdx.x;
  int n0 = blockIdx.y * BN;          // over D: 6 tiles
  int kbase = blockIdx.z * (M_DIM / 4);
  int off = offsets[e];
  int cnt = offsets[e + 1] - off;
  if (cnt == 0) return;

  __shared__ __align__(16) __bf16 Al[BM * LDS_STRIDE];
  __shared__ __align__(16) __bf16 Bl[BN * LDS_STRIDE];

  int tid = threadIdx.x;
  int w = tid >> 6, lane = tid & 63;
  int l31 = lane & 31, lh = lane >> 5;

  int sa_row = tid >> 2;
  int sa_kp = (tid & 3) * 8;
  int sb_n = tid & 127;
  int sb_kg = (tid >> 7) * 16;

  const float* Wb = W2 + (size_t)e * M_DIM * D_DIM + n0 + sb_n;
  const int NKT = (M_DIM / 4) / BKT; // 24

  for (int r0 = 0; r0 < cnt; r0 += BM) {
    f32x16 acc[2];
#pragma unroll
    for (int mt = 0; mt < 2; ++mt)
#pragma unroll
      for (int r = 0; r < 16; ++r) acc[mt][r] = 0.f;

    const __bf16* Arow = h + (size_t)(off + r0 + sa_row) * M_DIM + kbase + sa_kp;

    uint4 ra = *(const uint4*)Arow;
    float rb[16];
#pragma unroll
    for (int i = 0; i < 16; ++i) rb[i] = Wb[(size_t)(kbase + sb_kg + i) * D_DIM];

    for (int kt = 0; kt < NKT; ++kt) {
      __syncthreads();
      *(uint4*)(Al + sa_row * LDS_STRIDE + sa_kp) = ra;
      {
        bf16x8 lo, hi;
#pragma unroll
        for (int i = 0; i < 8; ++i) { lo[i] = (__bf16)rb[i]; hi[i] = (__bf16)rb[8 + i]; }
        *(bf16x8*)(Bl + sb_n * LDS_STRIDE + sb_kg) = lo;
        *(bf16x8*)(Bl + sb_n * LDS_STRIDE + sb_kg + 8) = hi;
      }
      uint4 ra_n = ra;
      float rb_n[16];
#pragma unroll
      for (int i = 0; i < 16; ++i) rb_n[i] = rb[i];
      if (kt + 1 < NKT) {
        int k0 = (kt + 1) * BKT;
        ra_n = *(const uint4*)(Arow + k0);
#pragma unroll
        for (int i = 0; i < 16; ++i)
          rb_n[i] = Wb[(size_t)(kbase + k0 + sb_kg + i) * D_DIM];
      }
      __syncthreads();
#pragma unroll
      for (int ks = 0; ks < 2; ++ks) {
        bf16x8 b  = *(bf16x8*)(Bl + (w * 32 + l31) * LDS_STRIDE + ks * 16 + lh * 8);
        bf16x8 a0 = *(bf16x8*)(Al + (l31) * LDS_STRIDE + ks * 16 + lh * 8);
        bf16x8 a1 = *(bf16x8*)(Al + (32 + l31) * LDS_STRIDE + ks * 16 + lh * 8);
        acc[0] = __builtin_amdgcn_mfma_f32_32x32x16_bf16(a0, b, acc[0], 0, 0, 0);
        acc[1] = __builtin_amdgcn_mfma_f32_32x32x16_bf16(a1, b, acc[1], 0, 0, 0);
      }
      ra = ra_n;
#pragma unroll
      for (int i = 0; i < 16; ++i) rb[i] = rb_n[i];
    }

    int col = n0 + w * 32 + l31;
    float bias = (blockIdx.z == 0) ? b2[e * D_DIM + col] : 0.f;
#pragma unroll
    for (int mt = 0; mt < 2; ++mt) {
#pragma unroll
      for (int r = 0; r < 16; ++r) {
        int row = mt * 32 + (r & 3) + 8 * (r >> 2) + 4 * lh;
        if (r0 + row < cnt) {
          int p = off + r0 + row;
          int t = tok_id[p];
          float wgt = tok_w[p];
          atomicAdd(&out[(size_t)t * D_DIM + col], wgt * (acc[mt][r] + bias));
        }
      }
    }
  }
}

// ---------------- launch ----------------
extern "C" void kernel_launch(void* const* d_in, const int* in_sizes, int n_in,
                              void* d_out, int out_size, void* d_ws, size_t ws_size,
                              hipStream_t stream) {
  const float* x   = (const float*)d_in[0];
  const float* Wg  = (const float*)d_in[1];
  const float* bg  = (const float*)d_in[2];
  const float* Wge = (const float*)d_in[3];
  const float* bge = (const float*)d_in[4];
  const float* W1  = (const float*)d_in[5];
  const float* b1  = (const float*)d_in[6];
  const float* W2  = (const float*)d_in[7];
  const float* b2  = (const float*)d_in[8];
  float* out = (float*)d_out;

  char* ws = (char*)d_ws;
  int*    counts  = (int*)(ws + 0);
  int*    counts2 = (int*)(ws + 128);
  int*    offsets = (int*)(ws + 256);
  int*    sel_e   = (int*)(ws + 512);
  float*  sel_w   = (float*)(ws + 8704);
  int*    tok_id  = (int*)(ws + 16896);
  float*  tok_w   = (float*)(ws + 25088);
  __bf16* Abuf    = (__bf16*)(ws + 33280);             // (2048+64) x 768 bf16
  __bf16* h       = (__bf16*)(ws + 33280 + 3244032);   // (2048+64) x 3072 bf16

  hipMemsetAsync(ws, 0, 256, stream);
  hipMemsetAsync(d_out, 0, (size_t)out_size * sizeof(float), stream);

  route_kernel<<<N_TOK, 64, 0, stream>>>(x, Wg, bg, Wge, bge, sel_e, sel_w, counts);
  scan_kernel<<<1, 64, 0, stream>>>(counts, offsets);
  fill_kernel<<<8, 64, 0, stream>>>(sel_e, sel_w, offsets, counts2, tok_id, tok_w);
  gather_kernel<<<2048, 192, 0, stream>>>(x, tok_id, Abuf);
  fc1_mfma<<<dim3(GE, M_DIM / BN), 256, 0, stream>>>(Abuf, W1, b1, offsets, h);
  fc2_mfma<<<dim3(GE, D_DIM / BN, 4), 256, 0, stream>>>(h, W2, b2, offsets, tok_id, tok_w, out);
}